// Round 11
// baseline (302.061 us; speedup 1.0000x reference)
//
#include <hip/hip_runtime.h>
#include <hip/hip_bf16.h>

// GAT layer, N=8192 Fin=256 Fout=64.
// v10: coalesced (R10) + TLP/occupancy push + deterministic partials.
//   k1: Wh=h@W; s1/s2 (s2 log2e-scaled); whT packed as MFMA A-frags (hi/lo).
//   k2: grid 2048 = (qi 0..255) x (jh 0..7 octants of 1024 j); 4 waves/block,
//       launch_bounds(256,6) -> 24 waves/CU. adj lane<->j coalesced; P built in
//       coalesced layout, transposed via wave-private LDS (pitch-38 ushort,
//       odd-dword -> all 32 banks); 1-deep adj prefetch, fully unrolled.
//       Partials written non-atomically to per-octant planes; k3 sums 8 planes,
//       divides, ELU. No memset, no atomics (deterministic).

typedef __attribute__((ext_vector_type(8))) short bf16x8;
typedef __attribute__((ext_vector_type(16))) float f32x16;

#define LOG2E 1.4426950408889634f

__device__ __forceinline__ uint pk2o(float a, float b) {
    __hip_bfloat162 h = __float22bfloat162_rn(make_float2(a, b));
    union { __hip_bfloat162 b; uint u; } c; c.b = h; return c.u;
}
__device__ __forceinline__ ushort f2bf(float x) {
    union { __hip_bfloat16 b; ushort u; } c;
    c.b = __float2bfloat16(x);
    return c.u;
}
__device__ __forceinline__ float bf2f(ushort u) {
    union { ushort u; __hip_bfloat16 b; } c;
    c.u = u;
    return __bfloat162float(c.b);
}

// ---------------- kernel 1: Wh, s1, s2*log2e, packed A-frags ----------------
__global__ __launch_bounds__(256) void k1_wh(
    const float* __restrict__ h, const float* __restrict__ W,
    const float* __restrict__ a,
    float* __restrict__ s1, float* __restrict__ s2,
    ushort* __restrict__ pw_hi, ushort* __restrict__ pw_lo)
{
    __shared__ ushort whh[16][64], whl[16][64];
    const int l = threadIdx.x & 63;      // lane = output feature
    const int w = threadIdx.x >> 6;
    const int b = blockIdx.x;
    const int row0 = b * 16 + w * 4;

    float acc[4] = {0.f, 0.f, 0.f, 0.f};
    for (int k = 0; k < 256; k += 4) {
        float w0 = W[(k + 0) * 64 + l];
        float w1 = W[(k + 1) * 64 + l];
        float w2 = W[(k + 2) * 64 + l];
        float w3 = W[(k + 3) * 64 + l];
#pragma unroll
        for (int r = 0; r < 4; ++r) {
            const float4 hv = *reinterpret_cast<const float4*>(&h[(row0 + r) * 256 + k]);
            acc[r] = fmaf(hv.x, w0, acc[r]);
            acc[r] = fmaf(hv.y, w1, acc[r]);
            acc[r] = fmaf(hv.z, w2, acc[r]);
            acc[r] = fmaf(hv.w, w3, acc[r]);
        }
    }
    const float a1 = a[l];
    const float a2 = a[64 + l];
#pragma unroll
    for (int r = 0; r < 4; ++r) {
        const int row = row0 + r;
        float x1 = acc[r] * a1;
        float x2 = acc[r] * a2;
#pragma unroll
        for (int m = 32; m >= 1; m >>= 1) {
            x1 += __shfl_xor(x1, m);
            x2 += __shfl_xor(x2, m);
        }
        if (l == 0) { s1[row] = x1; s2[row] = x2 * LOG2E; }
        const ushort hi = f2bf(acc[r]);
        const ushort lo = f2bf(acc[r] - bf2f(hi));
        whh[w * 4 + r][l] = hi;
        whl[w * 4 + r][l] = lo;
    }
    __syncthreads();
    // PW[jstep=b][ft][lane l] = wh[(l>>5)*8+e][ft*32+(l&31)], e=0..7
    const int ft = w & 1;
    const ushort (*src)[64] = (w < 2) ? whh : whl;
    ushort* dst = (w < 2) ? pw_hi : pw_lo;
    const int hh = l >> 5;
    union { bf16x8 v; ushort s[8]; } fr;
#pragma unroll
    for (int e = 0; e < 8; ++e)
        fr.s[e] = src[hh * 8 + e][ft * 32 + (l & 31)];
    *reinterpret_cast<bf16x8*>(&dst[(size_t)(b * 2 + ft) * 512 + l * 8]) = fr.v;
}

// ---------------- kernel 2: coalesced fused attention ----------------

#define PGRP(G, AV, RS) { \
    float t1_, t2_, p0_, p1_, p2_, p3_; \
    t1_ = Ag[G] + sv.x; t2_ = fmaf(0.2f, sv.x, A5g[G]); \
    p0_ = __builtin_amdgcn_exp2f(fmaxf(t1_, t2_)); if ((AV).x <= 0) p0_ = 0.f; \
    t1_ = Ag[G] + sv.y; t2_ = fmaf(0.2f, sv.y, A5g[G]); \
    p1_ = __builtin_amdgcn_exp2f(fmaxf(t1_, t2_)); if ((AV).y <= 0) p1_ = 0.f; \
    t1_ = Ag[G] + sv.z; t2_ = fmaf(0.2f, sv.z, A5g[G]); \
    p2_ = __builtin_amdgcn_exp2f(fmaxf(t1_, t2_)); if ((AV).z <= 0) p2_ = 0.f; \
    t1_ = Ag[G] + sv.w; t2_ = fmaf(0.2f, sv.w, A5g[G]); \
    p3_ = __builtin_amdgcn_exp2f(fmaxf(t1_, t2_)); if ((AV).w <= 0) p3_ = 0.f; \
    RS += (p0_ + p1_) + (p2_ + p3_); \
    *reinterpret_cast<uint2*>(&myp[(8 * (G) + g8) * 38 + jc]) = \
        make_uint2(pk2o(p0_, p1_), pk2o(p2_, p3_)); \
}

__global__ __launch_bounds__(256, 6) void k2_attn(
    const int* __restrict__ adj,
    const float* __restrict__ s1g, const float* __restrict__ s2g,
    const ushort* __restrict__ pw_hi, const ushort* __restrict__ pw_lo,
    float* __restrict__ pacc8, float* __restrict__ pden8)
{
    // smem: [0,4096) s2 octant f32 | [4096, 4096+4*2432) per-wave P (pitch 38)
    // [13824, 14336) dlds. Epilogue aliases [0,6144) as chunk slds [3][2][64][4].
    __shared__ __align__(16) unsigned char smem[14336];

    const int t   = threadIdx.x;
    const int l   = t & 63;
    const int wv  = t >> 6;
    const int qi  = blockIdx.x >> 3;
    const int jh  = blockIdx.x & 7;
    const int i0  = qi * 32;
    const int row = l & 31;           // B-frag row (MFMA role)
    const int kh  = l >> 5;           // k-half (MFMA role)
    const int g8  = l >> 3;           // row-in-octet (P role)
    const int jc  = (l & 7) * 4;      // j-offset (P role)

    float* s2l  = reinterpret_cast<float*>(smem);
    ushort* myp = reinterpret_cast<ushort*>(smem + 4096) + wv * 1216;
    float (*dlds)[32] = reinterpret_cast<float(*)[32]>(smem + 13824);

    // stage s2 octant (1024 floats, coalesced)
    reinterpret_cast<float4*>(s2l)[t] =
        reinterpret_cast<const float4*>(s2g + jh * 1024)[t];

    float Ag[4], A5g[4];
#pragma unroll
    for (int g = 0; g < 4; ++g) {
        const float s1v = s1g[i0 + 8 * g + g8];
        const float mq  = s1v + 16.0f;
        const float m   = fmaxf(mq, 0.2f * mq);
        Ag[g]  = (s1v - m) * LOG2E;
        A5g[g] = fmaf(0.2f, s1v, -m) * LOG2E;
    }
    __syncthreads();

    const int jb  = jh * 1024 + wv * 256;
    const int js0 = jb >> 4;
    const int* ap0 = adj + (size_t)(i0 + g8) * 8192 + jb + jc;
    const int* ap1 = ap0 + (size_t)8 * 8192;
    const int* ap2 = ap0 + (size_t)16 * 8192;
    const int* ap3 = ap0 + (size_t)24 * 8192;

    f32x16 acc0 = {0.f,0.f,0.f,0.f,0.f,0.f,0.f,0.f,0.f,0.f,0.f,0.f,0.f,0.f,0.f,0.f};
    f32x16 acc1 = {0.f,0.f,0.f,0.f,0.f,0.f,0.f,0.f,0.f,0.f,0.f,0.f,0.f,0.f,0.f,0.f};
    float rs0 = 0.f, rs1 = 0.f, rs2 = 0.f, rs3 = 0.f;

    // 1-deep prefetch rotation, fully unrolled (8 ms-iters of 32 j)
    int4 c0 = *reinterpret_cast<const int4*>(ap0);
    int4 c1 = *reinterpret_cast<const int4*>(ap1);
    int4 c2 = *reinterpret_cast<const int4*>(ap2);
    int4 c3 = *reinterpret_cast<const int4*>(ap3);

#pragma unroll
    for (int ms = 0; ms < 8; ++ms) {
        const int nm = (ms < 7) ? (ms + 1) * 32 : 7 * 32;
        const int4 n0 = *reinterpret_cast<const int4*>(ap0 + nm);
        const int4 n1 = *reinterpret_cast<const int4*>(ap1 + nm);
        const int4 n2 = *reinterpret_cast<const int4*>(ap2 + nm);
        const int4 n3 = *reinterpret_cast<const int4*>(ap3 + nm);
        const float4 sv = *reinterpret_cast<const float4*>(&s2l[wv * 256 + ms * 32 + jc]);

        PGRP(0, c0, rs0)
        PGRP(1, c1, rs1)
        PGRP(2, c2, rs2)
        PGRP(3, c3, rs3)

#pragma unroll
        for (int ksx = 0; ksx < 2; ++ksx) {
            const int js = js0 + ms * 2 + ksx;
            const bf16x8 ah0 = *reinterpret_cast<const bf16x8*>(&pw_hi[(size_t)(js * 2 + 0) * 512 + l * 8]);
            const bf16x8 al0 = *reinterpret_cast<const bf16x8*>(&pw_lo[(size_t)(js * 2 + 0) * 512 + l * 8]);
            const bf16x8 ah1 = *reinterpret_cast<const bf16x8*>(&pw_hi[(size_t)(js * 2 + 1) * 512 + l * 8]);
            const bf16x8 al1 = *reinterpret_cast<const bf16x8*>(&pw_lo[(size_t)(js * 2 + 1) * 512 + l * 8]);
            union { bf16x8 v; ushort4 q[2]; } bh;
            bh.q[0] = *reinterpret_cast<const ushort4*>(&myp[row * 38 + ksx * 16 + kh * 8]);
            bh.q[1] = *reinterpret_cast<const ushort4*>(&myp[row * 38 + ksx * 16 + kh * 8 + 4]);
            acc0 = __builtin_amdgcn_mfma_f32_32x32x16_bf16(ah0, bh.v, acc0, 0, 0, 0);
            acc0 = __builtin_amdgcn_mfma_f32_32x32x16_bf16(al0, bh.v, acc0, 0, 0, 0);
            acc1 = __builtin_amdgcn_mfma_f32_32x32x16_bf16(ah1, bh.v, acc1, 0, 0, 0);
            acc1 = __builtin_amdgcn_mfma_f32_32x32x16_bf16(al1, bh.v, acc1, 0, 0, 0);
        }
        c0 = n0; c1 = n1; c2 = n2; c3 = n3;
    }

    // ---- denominators: 8-lane reduce, per-wave rows into dlds ----
#define RED8(RS) RS += __shfl_xor(RS, 1); RS += __shfl_xor(RS, 2); RS += __shfl_xor(RS, 4);
    RED8(rs0) RED8(rs1) RED8(rs2) RED8(rs3)
    if ((l & 7) == 0) {
        dlds[wv][g8]      = rs0;
        dlds[wv][8 + g8]  = rs1;
        dlds[wv][16 + g8] = rs2;
        dlds[wv][24 + g8] = rs3;
    }
    __syncthreads();   // dlds ready; also retires myp/s2l before aliasing

    if (wv == 0 && l < 32)
        pden8[(size_t)jh * 8192 + i0 + l] =
            dlds[0][l] + dlds[1][l] + dlds[2][l] + dlds[3][l];

    // ---- cross-wave acc reduce in 4 chunks of 4 floats (6 KB alias) ----
    float* sldsc = reinterpret_cast<float*>(smem);   // [3][2][64][4]
#pragma unroll
    for (int c = 0; c < 4; ++c) {
        if (wv != 0) {
            float4* d0 = reinterpret_cast<float4*>(&sldsc[(((wv - 1) * 2 + 0) * 64 + l) * 4]);
            float4* d1 = reinterpret_cast<float4*>(&sldsc[(((wv - 1) * 2 + 1) * 64 + l) * 4]);
            *d0 = make_float4(acc0[c*4+0], acc0[c*4+1], acc0[c*4+2], acc0[c*4+3]);
            *d1 = make_float4(acc1[c*4+0], acc1[c*4+1], acc1[c*4+2], acc1[c*4+3]);
        }
        __syncthreads();
        if (wv == 0) {
#pragma unroll
            for (int s = 0; s < 3; ++s) {
                const float4 v0 = *reinterpret_cast<const float4*>(&sldsc[((s * 2 + 0) * 64 + l) * 4]);
                const float4 v1 = *reinterpret_cast<const float4*>(&sldsc[((s * 2 + 1) * 64 + l) * 4]);
                acc0[c*4+0] += v0.x; acc0[c*4+1] += v0.y; acc0[c*4+2] += v0.z; acc0[c*4+3] += v0.w;
                acc1[c*4+0] += v1.x; acc1[c*4+1] += v1.y; acc1[c*4+2] += v1.z; acc1[c*4+3] += v1.w;
            }
        }
        __syncthreads();
    }

    if (wv == 0) {
        // D layout (32x32): col=l&31 -> node row; feat-in-half = j + 8g + 4kh
        float* pb = pacc8 + ((size_t)jh * 8192 + i0 + row) * 64;
#pragma unroll
        for (int g = 0; g < 4; ++g) {
            *reinterpret_cast<float4*>(pb + 8 * g + 4 * kh) =
                make_float4(acc0[g*4+0], acc0[g*4+1], acc0[g*4+2], acc0[g*4+3]);
            *reinterpret_cast<float4*>(pb + 32 + 8 * g + 4 * kh) =
                make_float4(acc1[g*4+0], acc1[g*4+1], acc1[g*4+2], acc1[g*4+3]);
        }
    }
}

// ---------------- kernel 3: sum 8 octant planes, divide, ELU ----------------
__global__ __launch_bounds__(256) void k3_fin(
    const float* __restrict__ pacc8, const float* __restrict__ pden8,
    float* __restrict__ out)
{
    const int idx = blockIdx.x * 256 + threadIdx.x;   // 131072 float4-groups
    const int row = idx >> 4;
    float den = 0.f;
    float4 v = make_float4(0.f, 0.f, 0.f, 0.f);
#pragma unroll
    for (int p = 0; p < 8; ++p) {
        den += pden8[p * 8192 + row];
        const float4 u = reinterpret_cast<const float4*>(pacc8 + (size_t)p * 524288)[idx];
        v.x += u.x; v.y += u.y; v.z += u.z; v.w += u.w;
    }
    const float inv = 1.0f / den;
    float4 o; float x;
    x = v.x * inv; o.x = (x > 0.f) ? x : expm1f(x);
    x = v.y * inv; o.y = (x > 0.f) ? x : expm1f(x);
    x = v.z * inv; o.z = (x > 0.f) ? x : expm1f(x);
    x = v.w * inv; o.w = (x > 0.f) ? x : expm1f(x);
    reinterpret_cast<float4*>(out)[idx] = o;
}

extern "C" void kernel_launch(void* const* d_in, const int* in_sizes, int n_in,
                              void* d_out, int out_size, void* d_ws, size_t ws_size,
                              hipStream_t stream) {
    const float* h   = (const float*)d_in[0];
    const int*   adj = (const int*)d_in[1];
    const float* W   = (const float*)d_in[2];
    const float* a   = (const float*)d_in[3];
    float* out = (float*)d_out;

    float*  s1    = (float*)d_ws;                  // 8192 f32
    float*  s2    = s1 + 8192;                     // 8192 f32 (log2e-scaled)
    ushort* pw_hi = (ushort*)(s2 + 8192);          // 512 jsteps x 2 ft x 512 ushorts (1MB)
    ushort* pw_lo = pw_hi + 512 * 1024;            // 1MB
    float*  pacc8 = (float*)(pw_lo + 512 * 1024);  // [8][8192][64] f32 (16MB)
    float*  pden8 = pacc8 + 8 * 8192 * 64;         // [8][8192] f32

    hipLaunchKernelGGL(k1_wh, dim3(512), dim3(256), 0, stream,
                       h, W, a, s1, s2, pw_hi, pw_lo);
    hipLaunchKernelGGL(k2_attn, dim3(2048), dim3(256), 0, stream,
                       adj, s1, s2, pw_hi, pw_lo, pacc8, pden8);
    hipLaunchKernelGGL(k3_fin, dim3(512), dim3(256), 0, stream,
                       pacc8, pden8, out);
}

// Round 12
// 101.378 us; speedup vs baseline: 2.9795x; 2.9795x over previous
//
#include <hip/hip_runtime.h>
#include <hip/hip_bf16.h>

// GAT layer, N=8192 Fin=256 Fout=64.
// v11 = v10 with the spill fixed: launch_bounds(256,4) (R11's (256,6) capped
// VGPR at ~85 -> compiler spilled the f32x16 accumulators, WRITE_SIZE 523MB).
//   k1: Wh=h@W; s1/s2 (s2 log2e-scaled); whT packed as MFMA A-frags (hi/lo).
//   k2: grid 2048 = (qi 0..255) x (jh 0..7); 4 waves/block. adj lane<->j
//       coalesced; P built coalesced, transposed via wave-private LDS
//       (pitch-38 ushort, zero conflicts verified R11); 1-deep adj prefetch.
//       jh varies fastest -> per-XCD j-octant -> pw slice (256KB) L2-resident.
//       Partials to per-octant planes (no atomics/memset); k3 sums+div+ELU.

typedef __attribute__((ext_vector_type(8))) short bf16x8;
typedef __attribute__((ext_vector_type(16))) float f32x16;

#define LOG2E 1.4426950408889634f

__device__ __forceinline__ uint pk2o(float a, float b) {
    __hip_bfloat162 h = __float22bfloat162_rn(make_float2(a, b));
    union { __hip_bfloat162 b; uint u; } c; c.b = h; return c.u;
}
__device__ __forceinline__ ushort f2bf(float x) {
    union { __hip_bfloat16 b; ushort u; } c;
    c.b = __float2bfloat16(x);
    return c.u;
}
__device__ __forceinline__ float bf2f(ushort u) {
    union { ushort u; __hip_bfloat16 b; } c;
    c.u = u;
    return __bfloat162float(c.b);
}

// ---------------- kernel 1: Wh, s1, s2*log2e, packed A-frags ----------------
__global__ __launch_bounds__(256) void k1_wh(
    const float* __restrict__ h, const float* __restrict__ W,
    const float* __restrict__ a,
    float* __restrict__ s1, float* __restrict__ s2,
    ushort* __restrict__ pw_hi, ushort* __restrict__ pw_lo)
{
    __shared__ ushort whh[16][64], whl[16][64];
    const int l = threadIdx.x & 63;      // lane = output feature
    const int w = threadIdx.x >> 6;
    const int b = blockIdx.x;
    const int row0 = b * 16 + w * 4;

    float acc[4] = {0.f, 0.f, 0.f, 0.f};
    for (int k = 0; k < 256; k += 4) {
        float w0 = W[(k + 0) * 64 + l];
        float w1 = W[(k + 1) * 64 + l];
        float w2 = W[(k + 2) * 64 + l];
        float w3 = W[(k + 3) * 64 + l];
#pragma unroll
        for (int r = 0; r < 4; ++r) {
            const float4 hv = *reinterpret_cast<const float4*>(&h[(row0 + r) * 256 + k]);
            acc[r] = fmaf(hv.x, w0, acc[r]);
            acc[r] = fmaf(hv.y, w1, acc[r]);
            acc[r] = fmaf(hv.z, w2, acc[r]);
            acc[r] = fmaf(hv.w, w3, acc[r]);
        }
    }
    const float a1 = a[l];
    const float a2 = a[64 + l];
#pragma unroll
    for (int r = 0; r < 4; ++r) {
        const int row = row0 + r;
        float x1 = acc[r] * a1;
        float x2 = acc[r] * a2;
#pragma unroll
        for (int m = 32; m >= 1; m >>= 1) {
            x1 += __shfl_xor(x1, m);
            x2 += __shfl_xor(x2, m);
        }
        if (l == 0) { s1[row] = x1; s2[row] = x2 * LOG2E; }
        const ushort hi = f2bf(acc[r]);
        const ushort lo = f2bf(acc[r] - bf2f(hi));
        whh[w * 4 + r][l] = hi;
        whl[w * 4 + r][l] = lo;
    }
    __syncthreads();
    // PW[jstep=b][ft][lane l] = wh[(l>>5)*8+e][ft*32+(l&31)], e=0..7
    const int ft = w & 1;
    const ushort (*src)[64] = (w < 2) ? whh : whl;
    ushort* dst = (w < 2) ? pw_hi : pw_lo;
    const int hh = l >> 5;
    union { bf16x8 v; ushort s[8]; } fr;
#pragma unroll
    for (int e = 0; e < 8; ++e)
        fr.s[e] = src[hh * 8 + e][ft * 32 + (l & 31)];
    *reinterpret_cast<bf16x8*>(&dst[(size_t)(b * 2 + ft) * 512 + l * 8]) = fr.v;
}

// ---------------- kernel 2: coalesced fused attention ----------------

#define PGRP(G, AV, RS) { \
    float t1_, t2_, p0_, p1_, p2_, p3_; \
    t1_ = Ag[G] + sv.x; t2_ = fmaf(0.2f, sv.x, A5g[G]); \
    p0_ = __builtin_amdgcn_exp2f(fmaxf(t1_, t2_)); if ((AV).x <= 0) p0_ = 0.f; \
    t1_ = Ag[G] + sv.y; t2_ = fmaf(0.2f, sv.y, A5g[G]); \
    p1_ = __builtin_amdgcn_exp2f(fmaxf(t1_, t2_)); if ((AV).y <= 0) p1_ = 0.f; \
    t1_ = Ag[G] + sv.z; t2_ = fmaf(0.2f, sv.z, A5g[G]); \
    p2_ = __builtin_amdgcn_exp2f(fmaxf(t1_, t2_)); if ((AV).z <= 0) p2_ = 0.f; \
    t1_ = Ag[G] + sv.w; t2_ = fmaf(0.2f, sv.w, A5g[G]); \
    p3_ = __builtin_amdgcn_exp2f(fmaxf(t1_, t2_)); if ((AV).w <= 0) p3_ = 0.f; \
    RS += (p0_ + p1_) + (p2_ + p3_); \
    *reinterpret_cast<uint2*>(&myp[(8 * (G) + g8) * 38 + jc]) = \
        make_uint2(pk2o(p0_, p1_), pk2o(p2_, p3_)); \
}

__global__ __launch_bounds__(256, 4) void k2_attn(
    const int* __restrict__ adj,
    const float* __restrict__ s1g, const float* __restrict__ s2g,
    const ushort* __restrict__ pw_hi, const ushort* __restrict__ pw_lo,
    float* __restrict__ pacc8, float* __restrict__ pden8)
{
    // smem: [0,4096) s2 octant f32 | [4096, 4096+4*2432) per-wave P (pitch 38)
    // [13824, 14336) dlds. Epilogue aliases [0,6144) as chunk slds [3][2][64][4].
    __shared__ __align__(16) unsigned char smem[14336];

    const int t   = threadIdx.x;
    const int l   = t & 63;
    const int wv  = t >> 6;
    const int qi  = blockIdx.x >> 3;
    const int jh  = blockIdx.x & 7;
    const int i0  = qi * 32;
    const int row = l & 31;           // B-frag row (MFMA role)
    const int kh  = l >> 5;           // k-half (MFMA role)
    const int g8  = l >> 3;           // row-in-octet (P role)
    const int jc  = (l & 7) * 4;      // j-offset (P role)

    float* s2l  = reinterpret_cast<float*>(smem);
    ushort* myp = reinterpret_cast<ushort*>(smem + 4096) + wv * 1216;
    float (*dlds)[32] = reinterpret_cast<float(*)[32]>(smem + 13824);

    // stage s2 octant (1024 floats, coalesced)
    reinterpret_cast<float4*>(s2l)[t] =
        reinterpret_cast<const float4*>(s2g + jh * 1024)[t];

    float Ag[4], A5g[4];
#pragma unroll
    for (int g = 0; g < 4; ++g) {
        const float s1v = s1g[i0 + 8 * g + g8];
        const float mq  = s1v + 16.0f;
        const float m   = fmaxf(mq, 0.2f * mq);
        Ag[g]  = (s1v - m) * LOG2E;
        A5g[g] = fmaf(0.2f, s1v, -m) * LOG2E;
    }
    __syncthreads();

    const int jb  = jh * 1024 + wv * 256;
    const int js0 = jb >> 4;
    const int* ap0 = adj + (size_t)(i0 + g8) * 8192 + jb + jc;
    const int* ap1 = ap0 + (size_t)8 * 8192;
    const int* ap2 = ap0 + (size_t)16 * 8192;
    const int* ap3 = ap0 + (size_t)24 * 8192;

    f32x16 acc0 = {0.f,0.f,0.f,0.f,0.f,0.f,0.f,0.f,0.f,0.f,0.f,0.f,0.f,0.f,0.f,0.f};
    f32x16 acc1 = {0.f,0.f,0.f,0.f,0.f,0.f,0.f,0.f,0.f,0.f,0.f,0.f,0.f,0.f,0.f,0.f};
    float rs0 = 0.f, rs1 = 0.f, rs2 = 0.f, rs3 = 0.f;

    // 1-deep prefetch rotation, fully unrolled (8 ms-iters of 32 j)
    int4 c0 = *reinterpret_cast<const int4*>(ap0);
    int4 c1 = *reinterpret_cast<const int4*>(ap1);
    int4 c2 = *reinterpret_cast<const int4*>(ap2);
    int4 c3 = *reinterpret_cast<const int4*>(ap3);

#pragma unroll
    for (int ms = 0; ms < 8; ++ms) {
        const int nm = (ms < 7) ? (ms + 1) * 32 : 7 * 32;
        const int4 n0 = *reinterpret_cast<const int4*>(ap0 + nm);
        const int4 n1 = *reinterpret_cast<const int4*>(ap1 + nm);
        const int4 n2 = *reinterpret_cast<const int4*>(ap2 + nm);
        const int4 n3 = *reinterpret_cast<const int4*>(ap3 + nm);
        const float4 sv = *reinterpret_cast<const float4*>(&s2l[wv * 256 + ms * 32 + jc]);

        PGRP(0, c0, rs0)
        PGRP(1, c1, rs1)
        PGRP(2, c2, rs2)
        PGRP(3, c3, rs3)

#pragma unroll
        for (int ksx = 0; ksx < 2; ++ksx) {
            const int js = js0 + ms * 2 + ksx;
            const bf16x8 ah0 = *reinterpret_cast<const bf16x8*>(&pw_hi[(size_t)(js * 2 + 0) * 512 + l * 8]);
            const bf16x8 al0 = *reinterpret_cast<const bf16x8*>(&pw_lo[(size_t)(js * 2 + 0) * 512 + l * 8]);
            const bf16x8 ah1 = *reinterpret_cast<const bf16x8*>(&pw_hi[(size_t)(js * 2 + 1) * 512 + l * 8]);
            const bf16x8 al1 = *reinterpret_cast<const bf16x8*>(&pw_lo[(size_t)(js * 2 + 1) * 512 + l * 8]);
            union { bf16x8 v; ushort4 q[2]; } bh;
            bh.q[0] = *reinterpret_cast<const ushort4*>(&myp[row * 38 + ksx * 16 + kh * 8]);
            bh.q[1] = *reinterpret_cast<const ushort4*>(&myp[row * 38 + ksx * 16 + kh * 8 + 4]);
            acc0 = __builtin_amdgcn_mfma_f32_32x32x16_bf16(ah0, bh.v, acc0, 0, 0, 0);
            acc0 = __builtin_amdgcn_mfma_f32_32x32x16_bf16(al0, bh.v, acc0, 0, 0, 0);
            acc1 = __builtin_amdgcn_mfma_f32_32x32x16_bf16(ah1, bh.v, acc1, 0, 0, 0);
            acc1 = __builtin_amdgcn_mfma_f32_32x32x16_bf16(al1, bh.v, acc1, 0, 0, 0);
        }
        c0 = n0; c1 = n1; c2 = n2; c3 = n3;
    }

    // ---- denominators: 8-lane reduce, per-wave rows into dlds ----
#define RED8(RS) RS += __shfl_xor(RS, 1); RS += __shfl_xor(RS, 2); RS += __shfl_xor(RS, 4);
    RED8(rs0) RED8(rs1) RED8(rs2) RED8(rs3)
    if ((l & 7) == 0) {
        dlds[wv][g8]      = rs0;
        dlds[wv][8 + g8]  = rs1;
        dlds[wv][16 + g8] = rs2;
        dlds[wv][24 + g8] = rs3;
    }
    __syncthreads();   // dlds ready; also retires myp/s2l before aliasing

    if (wv == 0 && l < 32)
        pden8[(size_t)jh * 8192 + i0 + l] =
            dlds[0][l] + dlds[1][l] + dlds[2][l] + dlds[3][l];

    // ---- cross-wave acc reduce in 4 chunks of 4 floats (6 KB alias) ----
    float* sldsc = reinterpret_cast<float*>(smem);   // [3][2][64][4]
#pragma unroll
    for (int c = 0; c < 4; ++c) {
        if (wv != 0) {
            float4* d0 = reinterpret_cast<float4*>(&sldsc[(((wv - 1) * 2 + 0) * 64 + l) * 4]);
            float4* d1 = reinterpret_cast<float4*>(&sldsc[(((wv - 1) * 2 + 1) * 64 + l) * 4]);
            *d0 = make_float4(acc0[c*4+0], acc0[c*4+1], acc0[c*4+2], acc0[c*4+3]);
            *d1 = make_float4(acc1[c*4+0], acc1[c*4+1], acc1[c*4+2], acc1[c*4+3]);
        }
        __syncthreads();
        if (wv == 0) {
#pragma unroll
            for (int s = 0; s < 3; ++s) {
                const float4 v0 = *reinterpret_cast<const float4*>(&sldsc[((s * 2 + 0) * 64 + l) * 4]);
                const float4 v1 = *reinterpret_cast<const float4*>(&sldsc[((s * 2 + 1) * 64 + l) * 4]);
                acc0[c*4+0] += v0.x; acc0[c*4+1] += v0.y; acc0[c*4+2] += v0.z; acc0[c*4+3] += v0.w;
                acc1[c*4+0] += v1.x; acc1[c*4+1] += v1.y; acc1[c*4+2] += v1.z; acc1[c*4+3] += v1.w;
            }
        }
        __syncthreads();
    }

    if (wv == 0) {
        // D layout (32x32): col=l&31 -> node row; feat-in-half = j + 8g + 4kh
        float* pb = pacc8 + ((size_t)jh * 8192 + i0 + row) * 64;
#pragma unroll
        for (int g = 0; g < 4; ++g) {
            *reinterpret_cast<float4*>(pb + 8 * g + 4 * kh) =
                make_float4(acc0[g*4+0], acc0[g*4+1], acc0[g*4+2], acc0[g*4+3]);
            *reinterpret_cast<float4*>(pb + 32 + 8 * g + 4 * kh) =
                make_float4(acc1[g*4+0], acc1[g*4+1], acc1[g*4+2], acc1[g*4+3]);
        }
    }
}

// ---------------- kernel 3: sum 8 octant planes, divide, ELU ----------------
__global__ __launch_bounds__(256) void k3_fin(
    const float* __restrict__ pacc8, const float* __restrict__ pden8,
    float* __restrict__ out)
{
    const int idx = blockIdx.x * 256 + threadIdx.x;   // 131072 float4-groups
    const int row = idx >> 4;
    float den = 0.f;
    float4 v = make_float4(0.f, 0.f, 0.f, 0.f);
#pragma unroll
    for (int p = 0; p < 8; ++p) {
        den += pden8[p * 8192 + row];
        const float4 u = reinterpret_cast<const float4*>(pacc8 + (size_t)p * 524288)[idx];
        v.x += u.x; v.y += u.y; v.z += u.z; v.w += u.w;
    }
    const float inv = 1.0f / den;
    float4 o; float x;
    x = v.x * inv; o.x = (x > 0.f) ? x : expm1f(x);
    x = v.y * inv; o.y = (x > 0.f) ? x : expm1f(x);
    x = v.z * inv; o.z = (x > 0.f) ? x : expm1f(x);
    x = v.w * inv; o.w = (x > 0.f) ? x : expm1f(x);
    reinterpret_cast<float4*>(out)[idx] = o;
}

extern "C" void kernel_launch(void* const* d_in, const int* in_sizes, int n_in,
                              void* d_out, int out_size, void* d_ws, size_t ws_size,
                              hipStream_t stream) {
    const float* h   = (const float*)d_in[0];
    const int*   adj = (const int*)d_in[1];
    const float* W   = (const float*)d_in[2];
    const float* a   = (const float*)d_in[3];
    float* out = (float*)d_out;

    float*  s1    = (float*)d_ws;                  // 8192 f32
    float*  s2    = s1 + 8192;                     // 8192 f32 (log2e-scaled)
    ushort* pw_hi = (ushort*)(s2 + 8192);          // 512 jsteps x 2 ft x 512 ushorts (1MB)
    ushort* pw_lo = pw_hi + 512 * 1024;            // 1MB
    float*  pacc8 = (float*)(pw_lo + 512 * 1024);  // [8][8192][64] f32 (16MB)
    float*  pden8 = pacc8 + 8 * 8192 * 64;         // [8][8192] f32

    hipLaunchKernelGGL(k1_wh, dim3(512), dim3(256), 0, stream,
                       h, W, a, s1, s2, pw_hi, pw_lo);
    hipLaunchKernelGGL(k2_attn, dim3(2048), dim3(256), 0, stream,
                       adj, s1, s2, pw_hi, pw_lo, pacc8, pden8);
    hipLaunchKernelGGL(k3_fin, dim3(512), dim3(256), 0, stream,
                       pacc8, pden8, out);
}